// Round 5
// baseline (2129.156 us; speedup 1.0000x reference)
//
#include <hip/hip_runtime.h>
#include <hip/hip_bf16.h>
#include <math.h>

#define N_NODES 50000
#define N_EDGES 800000
#define HID 128
#define OUT_DIM 40
#define BN_EPS 1e-5f

// ---------------------------------------------------------------------------
// deg counting (by dst), +1 self-loop added in dinv kernel
__global__ __launch_bounds__(256) void count_deg_kernel(const int* __restrict__ dst,
                                                        unsigned* __restrict__ deg, int E) {
    int e = blockIdx.x * blockDim.x + threadIdx.x;
    if (e < E) atomicAdd(&deg[dst[e]], 1u);
}

__global__ __launch_bounds__(256) void dinv_kernel(const unsigned* __restrict__ deg,
                                                   float* __restrict__ dinv, int n) {
    int v = blockIdx.x * blockDim.x + threadIdx.x;
    if (v < n) dinv[v] = rsqrtf((float)(deg[v] + 1u));
}

// h0 = alpha * x[:, :128] + beta * x[:, 128:]
__global__ __launch_bounds__(256) void init_h_kernel(const float* __restrict__ x,
                                                     const float* __restrict__ log_alpha,
                                                     const float* __restrict__ log_beta,
                                                     float* __restrict__ h, int n) {
    int gid = blockIdx.x * blockDim.x + threadIdx.x;
    if (gid >= n * HID) return;
    int v = gid >> 7, c = gid & 127;
    float alpha = expf(log_alpha[0]);
    float beta  = expf(log_beta[0]);
    const float* xr = x + (size_t)v * (2 * HID);
    h[gid] = alpha * xr[c] + beta * xr[HID + c];
}

// ---------------------------------------------------------------------------
// C[n x 128] = act(A[n x 128] @ W[128 x 128] + bias)
// W staged fully in LDS (64 KB). 256 threads: 2 rows in flight, thread -> col.
#define GEMM_ROWS 64
__global__ __launch_bounds__(256) void gemm128_kernel(const float* __restrict__ A,
                                                      const float* __restrict__ W,
                                                      const float* __restrict__ bias,
                                                      float* __restrict__ C,
                                                      int n, int do_relu) {
    __shared__ float Wl[HID * HID];
    for (int i = threadIdx.x; i < HID * HID / 4; i += blockDim.x)
        ((float4*)Wl)[i] = ((const float4*)W)[i];
    __syncthreads();

    int col  = threadIdx.x & 127;
    int half = threadIdx.x >> 7;  // 0 or 1
    int row0 = blockIdx.x * GEMM_ROWS;
    int rend = min(row0 + GEMM_ROWS, n);

    for (int r = row0 + half; r < rend; r += 2) {
        const float4* a4 = (const float4*)(A + (size_t)r * HID);
        float acc = bias ? bias[col] : 0.0f;
#pragma unroll
        for (int k4 = 0; k4 < HID / 4; ++k4) {
            float4 av = a4[k4];
            int k = k4 * 4;
            acc = fmaf(av.x, Wl[(k + 0) * HID + col], acc);
            acc = fmaf(av.y, Wl[(k + 1) * HID + col], acc);
            acc = fmaf(av.z, Wl[(k + 2) * HID + col], acc);
            acc = fmaf(av.w, Wl[(k + 3) * HID + col], acc);
        }
        if (do_relu) acc = fmaxf(acc, 0.0f);
        C[(size_t)r * HID + col] = acc;
    }
}

// ---------------------------------------------------------------------------
// out[v] = conv_b + m[v] * dinv[v]^2   (self-loop term, also initializes out)
__global__ __launch_bounds__(256) void agg_self_kernel(const float* __restrict__ m,
                                                       const float* __restrict__ dinv,
                                                       const float* __restrict__ conv_b,
                                                       float* __restrict__ out, int n) {
    int gid = blockIdx.x * blockDim.x + threadIdx.x;
    if (gid >= n * HID) return;
    int v = gid >> 7, c = gid & 127;
    float d = dinv[v];
    out[gid] = conv_b[c] + m[gid] * d * d;
}

// out[dst] += m[src] * dinv[src]*dinv[dst]  over real edges (atomic scatter)
__global__ __launch_bounds__(256) void agg_edges_kernel(const float* __restrict__ m,
                                                        const float* __restrict__ dinv,
                                                        const int* __restrict__ src,
                                                        const int* __restrict__ dst,
                                                        float* __restrict__ out, int E) {
    long long gid = (long long)blockIdx.x * blockDim.x + threadIdx.x;
    if (gid >= (long long)E * HID) return;
    int e = (int)(gid >> 7), c = (int)(gid & 127);
    int s = src[e], d = dst[e];
    float w = dinv[s] * dinv[d];
    atomicAdd(&out[(size_t)d * HID + c], m[(size_t)s * HID + c] * w);
}

// ---------------------------------------------------------------------------
// per-column sum and sumsq -> stats[0:128] = sum, stats[128:256] = sumsq
__global__ __launch_bounds__(256) void bn_stats_kernel(const float* __restrict__ h,
                                                       float* __restrict__ stats, int n) {
    int c = threadIdx.x & 127;
    int rt = (blockIdx.x * blockDim.x + threadIdx.x) >> 7;
    int rstride = (gridDim.x * blockDim.x) >> 7;
    float s = 0.0f, s2 = 0.0f;
    for (int r = rt; r < n; r += rstride) {
        float v = h[(size_t)r * HID + c];
        s += v; s2 += v * v;
    }
    atomicAdd(&stats[c], s);
    atomicAdd(&stats[HID + c], s2);
}

__global__ __launch_bounds__(256) void bn_apply_kernel(float* __restrict__ h,
                                                       const float* __restrict__ stats,
                                                       const float* __restrict__ gamma,
                                                       const float* __restrict__ beta,
                                                       int n) {
    int gid = blockIdx.x * blockDim.x + threadIdx.x;
    if (gid >= n * HID) return;
    int c = gid & 127;
    float inv_n = 1.0f / (float)n;
    float mean = stats[c] * inv_n;
    float var  = stats[HID + c] * inv_n - mean * mean;
    float sc = gamma[c] * rsqrtf(var + BN_EPS);
    float sh = beta[c] - mean * sc;
    h[gid] = fmaxf(h[gid] * sc + sh, 0.0f);
}

// ---------------------------------------------------------------------------
// logits = h @ lin_w + lin_b, then log_softmax.  One 64-lane wave per row,
// lanes 0..39 own one output column each.
__global__ __launch_bounds__(256) void final_kernel(const float* __restrict__ h,
                                                    const float* __restrict__ lw,
                                                    const float* __restrict__ lb,
                                                    float* __restrict__ out, int n) {
    int wave = (int)((blockIdx.x * blockDim.x + threadIdx.x) >> 6);
    int lane = threadIdx.x & 63;
    if (wave >= n) return;
    const float* hr = h + (size_t)wave * HID;
    float logit = 0.0f;
    if (lane < OUT_DIM) {
        logit = lb[lane];
#pragma unroll 4
        for (int k = 0; k < HID; ++k)
            logit = fmaf(hr[k], lw[k * OUT_DIM + lane], logit);
    }
    float mx = (lane < OUT_DIM) ? logit : -INFINITY;
    for (int off = 32; off; off >>= 1) mx = fmaxf(mx, __shfl_xor(mx, off));
    float ex = (lane < OUT_DIM) ? expf(logit - mx) : 0.0f;
    float sum = ex;
    for (int off = 32; off; off >>= 1) sum += __shfl_xor(sum, off);
    if (lane < OUT_DIM) out[(size_t)wave * OUT_DIM + lane] = logit - mx - logf(sum);
}

// ---------------------------------------------------------------------------
extern "C" void kernel_launch(void* const* d_in, const int* in_sizes, int n_in,
                              void* d_out, int out_size, void* d_ws, size_t ws_size,
                              hipStream_t stream) {
    const float* x         = (const float*)d_in[0];
    const int*   ei        = (const int*)d_in[1];
    const float* log_alpha = (const float*)d_in[2];
    const float* log_beta  = (const float*)d_in[3];
    const float* mlp_w     = (const float*)d_in[4];
    const float* mlp_b     = (const float*)d_in[5];
    const float* conv_w    = (const float*)d_in[6];
    const float* conv_b    = (const float*)d_in[7];
    const float* bn_gamma  = (const float*)d_in[8];
    const float* bn_beta   = (const float*)d_in[9];
    const float* lin_w     = (const float*)d_in[10];
    const float* lin_b     = (const float*)d_in[11];
    float* out = (float*)d_out;

    const int n = N_NODES, E = N_EDGES;
    const int* src = ei;
    const int* dst = ei + E;

    // workspace layout
    char* ws = (char*)d_ws;
    size_t hbytes = (size_t)n * HID * sizeof(float);  // 25.6 MB
    float* hA = (float*)(ws);                          // current h
    float* hB = (float*)(ws + hbytes);                 // mlp output
    float* hC = (float*)(ws + 2 * hbytes);             // conv linear output (m)
    unsigned* deg = (unsigned*)(ws + 3 * hbytes);
    float* dinv   = (float*)(ws + 3 * hbytes + (size_t)n * 4);
    float* stats  = (float*)(ws + 3 * hbytes + (size_t)n * 8);  // 2 layers x 256 floats

    hipMemsetAsync(deg, 0, (size_t)n * 4, stream);
    hipMemsetAsync(stats, 0, 512 * sizeof(float), stream);

    const int B = 256;
    count_deg_kernel<<<(E + B - 1) / B, B, 0, stream>>>(dst, deg, E);
    dinv_kernel<<<(n + B - 1) / B, B, 0, stream>>>(deg, dinv, n);
    init_h_kernel<<<(n * HID + B - 1) / B, B, 0, stream>>>(x, log_alpha, log_beta, hA, n);

    int gemm_grid = (n + GEMM_ROWS - 1) / GEMM_ROWS;
    long long ethreads = (long long)E * HID;
    int egrid = (int)((ethreads + B - 1) / B);
    int ngrid = (n * HID + B - 1) / B;

    for (int i = 0; i < 3; ++i) {
        // h = relu(h @ mlp_w[i] + mlp_b[i])
        gemm128_kernel<<<gemm_grid, B, 0, stream>>>(hA, mlp_w + (size_t)i * HID * HID,
                                                    mlp_b + (size_t)i * HID, hB, n, 1);
        // m = h @ conv_w[i]
        gemm128_kernel<<<gemm_grid, B, 0, stream>>>(hB, conv_w + (size_t)i * HID * HID,
                                                    nullptr, hC, n, 0);
        // h = segment_sum(m[src]*norm, dst) + conv_b[i]
        agg_self_kernel<<<ngrid, B, 0, stream>>>(hC, dinv, conv_b + (size_t)i * HID, hA, n);
        agg_edges_kernel<<<egrid, B, 0, stream>>>(hC, dinv, src, dst, hA, E);
        if (i < 2) {
            float* st = stats + (size_t)i * 256;
            bn_stats_kernel<<<512, B, 0, stream>>>(hA, st, n);
            bn_apply_kernel<<<ngrid, B, 0, stream>>>(hA, st, bn_gamma + (size_t)i * HID,
                                                     bn_beta + (size_t)i * HID, n);
        }
    }

    final_kernel<<<(n * 64 + B - 1) / B, B, 0, stream>>>(hA, lin_w, lin_b, out, n);
}

// Round 8
// 785.795 us; speedup vs baseline: 2.7096x; 2.7096x over previous
//
#include <hip/hip_runtime.h>
#include <hip/hip_bf16.h>
#include <math.h>

#define N_NODES 50000
#define N_EDGES 800000
#define HID 128
#define OUT_DIM 40
#define BN_EPS 1e-5f

// ---------------------------------------------------------------------------
// degree count by dst (real edges only; +1 self-loop applied in dinv)
__global__ __launch_bounds__(256) void count_deg_kernel(const int* __restrict__ dst,
                                                        unsigned* __restrict__ deg, int E) {
    int e = blockIdx.x * blockDim.x + threadIdx.x;
    if (e < E) atomicAdd(&deg[dst[e]], 1u);
}

__global__ __launch_bounds__(256) void dinv_kernel(const unsigned* __restrict__ deg,
                                                   float* __restrict__ dinv, int n) {
    int v = blockIdx.x * blockDim.x + threadIdx.x;
    if (v < n) dinv[v] = rsqrtf((float)(deg[v] + 1u));
}

// ---------------------------------------------------------------------------
// CSR build: 3-kernel exclusive scan of deg -> rowptr, then bucket fill.
// scan chunking: 1024 elements per block, 256 threads x 4 elems each.
#define SCAN_CHUNK 1024

__global__ __launch_bounds__(256) void scan_partial_kernel(const unsigned* __restrict__ deg,
                                                           unsigned* __restrict__ bsum, int n) {
    __shared__ unsigned sd[256];
    int base = blockIdx.x * SCAN_CHUNK;
    unsigned s = 0;
    for (int i = threadIdx.x; i < SCAN_CHUNK; i += 256) {
        int idx = base + i;
        if (idx < n) s += deg[idx];
    }
    sd[threadIdx.x] = s;
    __syncthreads();
    for (int off = 128; off; off >>= 1) {
        if (threadIdx.x < off) sd[threadIdx.x] += sd[threadIdx.x + off];
        __syncthreads();
    }
    if (threadIdx.x == 0) bsum[blockIdx.x] = sd[0];
}

// nb <= 64: single-thread exclusive scan (trivial work)
__global__ void scan_bsums_kernel(unsigned* __restrict__ bsum, int nb) {
    if (blockIdx.x == 0 && threadIdx.x == 0) {
        unsigned acc = 0;
        for (int i = 0; i < nb; ++i) { unsigned v = bsum[i]; bsum[i] = acc; acc += v; }
    }
}

// per-chunk exclusive scan -> rowptr[idx]; ALSO overwrites deg[idx] with the same
// value to serve as the csr_fill cursor. Sets rowptr[n] = E.
__global__ __launch_bounds__(256) void scan_chunk_kernel(unsigned* __restrict__ deg,
                                                         const unsigned* __restrict__ bsum,
                                                         unsigned* __restrict__ rowptr, int n) {
    __shared__ unsigned ts[256];
    int base = blockIdx.x * SCAN_CHUNK;
    int i0 = base + threadIdx.x * 4;
    unsigned v[4]; unsigned s = 0;
#pragma unroll
    for (int j = 0; j < 4; ++j) {
        int idx = i0 + j;
        v[j] = (idx < n) ? deg[idx] : 0u;
        s += v[j];
    }
    ts[threadIdx.x] = s;
    __syncthreads();
    // Hillis-Steele inclusive scan over 256 thread sums
    for (int off = 1; off < 256; off <<= 1) {
        unsigned add = (threadIdx.x >= (unsigned)off) ? ts[threadIdx.x - off] : 0u;
        __syncthreads();
        ts[threadIdx.x] += add;
        __syncthreads();
    }
    unsigned texcl = (threadIdx.x == 0) ? 0u : ts[threadIdx.x - 1];
    unsigned run = bsum[blockIdx.x] + texcl;
#pragma unroll
    for (int j = 0; j < 4; ++j) {
        int idx = i0 + j;
        if (idx < n) {
            rowptr[idx] = run;
            deg[idx] = run;          // cursor for csr_fill
            run += v[j];
            if (idx == n - 1) rowptr[n] = run;
        }
    }
}

__global__ __launch_bounds__(256) void csr_fill_kernel(const int* __restrict__ src,
                                                       const int* __restrict__ dst,
                                                       unsigned* __restrict__ cursor,
                                                       int* __restrict__ ecol, int E) {
    int e = blockIdx.x * blockDim.x + threadIdx.x;
    if (e >= E) return;
    unsigned pos = atomicAdd(&cursor[dst[e]], 1u);
    ecol[pos] = src[e];
}

// ---------------------------------------------------------------------------
// h0 = alpha * x[:, :128] + beta * x[:, 128:]
__global__ __launch_bounds__(256) void init_h_kernel(const float* __restrict__ x,
                                                     const float* __restrict__ log_alpha,
                                                     const float* __restrict__ log_beta,
                                                     float* __restrict__ h, int n) {
    int gid = blockIdx.x * blockDim.x + threadIdx.x;
    if (gid >= n * HID) return;
    int v = gid >> 7, c = gid & 127;
    float alpha = expf(log_alpha[0]);
    float beta  = expf(log_beta[0]);
    const float* xr = x + (size_t)v * (2 * HID);
    h[gid] = alpha * xr[c] + beta * xr[HID + c];
}

// ---------------------------------------------------------------------------
// GEMM v2: C[n x 128] = act(A @ W + bias). A-tile (64x128, 32 KB) in LDS;
// W (64 KB) read from L1/L2 via float4 (fully cache-resident, every block
// reads it). Thread = 4 cols (q) x 8 rows (rg): per k-step 8 broadcast
// ds_read_b32 + 1 coalesced global float4 + 32 FMA -> VALU-bound.
#define BM 64
__global__ __launch_bounds__(256) void gemm128_v2_kernel(const float* __restrict__ A,
                                                         const float* __restrict__ W,
                                                         const float* __restrict__ bias,
                                                         float* __restrict__ C,
                                                         int n, int do_relu) {
    __shared__ float As[BM][HID];  // 32 KB
    int row0 = blockIdx.x * BM;
    int nrow = min(BM, n - row0);
    {
        const float4* Ag = (const float4*)(A + (size_t)row0 * HID);
        float4* As4 = (float4*)&As[0][0];
        int n4 = nrow * (HID / 4);
        for (int i = threadIdx.x; i < n4; i += 256) As4[i] = Ag[i];
    }
    __syncthreads();

    int q  = threadIdx.x & 31;   // col quad: cols 4q..4q+3
    int rg = threadIdx.x >> 5;   // row group 0..7 -> rows 8rg..8rg+7
    int r0 = rg * 8;
    const float4* W4 = (const float4*)W;  // W4[k*32+q]

    float4 acc[8];
    float4 bv = make_float4(0.f, 0.f, 0.f, 0.f);
    if (bias) bv = ((const float4*)bias)[q];
#pragma unroll
    for (int i = 0; i < 8; ++i) acc[i] = bv;

#pragma unroll 4
    for (int k = 0; k < HID; ++k) {
        float4 w = W4[k * 32 + q];
#pragma unroll
        for (int i = 0; i < 8; ++i) {
            float a = As[r0 + i][k];
            acc[i].x = fmaf(a, w.x, acc[i].x);
            acc[i].y = fmaf(a, w.y, acc[i].y);
            acc[i].z = fmaf(a, w.z, acc[i].z);
            acc[i].w = fmaf(a, w.w, acc[i].w);
        }
    }

#pragma unroll
    for (int i = 0; i < 8; ++i) {
        int r = row0 + r0 + i;
        if (r < n) {
            float4 o = acc[i];
            if (do_relu) {
                o.x = fmaxf(o.x, 0.f); o.y = fmaxf(o.y, 0.f);
                o.z = fmaxf(o.z, 0.f); o.w = fmaxf(o.w, 0.f);
            }
            ((float4*)(C + (size_t)r * HID))[q] = o;
        }
    }
}

// ---------------------------------------------------------------------------
// CSR aggregation, one 128-thread block per node:
// out[v][c] = conv_b[c] + m[v][c]*dinv[v]^2 + sum_in-edges dinv[s]*dinv[v]*m[s][c]
__global__ __launch_bounds__(128) void agg_csr_kernel(const float* __restrict__ m,
                                                      const float* __restrict__ dinv,
                                                      const float* __restrict__ conv_b,
                                                      const unsigned* __restrict__ rowptr,
                                                      const int* __restrict__ ecol,
                                                      float* __restrict__ out) {
    int v = blockIdx.x;
    int c = threadIdx.x;
    float dv = dinv[v];
    float acc = conv_b[c] + m[(size_t)v * HID + c] * dv * dv;
    unsigned start = rowptr[v];
    unsigned end   = rowptr[v + 1];
    unsigned i = start;
    // 2-wide to break the ecol->m dependent-load chain
    for (; i + 1 < end; i += 2) {
        int s0 = ecol[i], s1 = ecol[i + 1];
        float w0 = dinv[s0] * dv, w1 = dinv[s1] * dv;
        acc = fmaf(w0, m[(size_t)s0 * HID + c], acc);
        acc = fmaf(w1, m[(size_t)s1 * HID + c], acc);
    }
    if (i < end) {
        int s0 = ecol[i];
        acc = fmaf(dinv[s0] * dv, m[(size_t)s0 * HID + c], acc);
    }
    out[(size_t)v * HID + c] = acc;
}

// ---------------------------------------------------------------------------
__global__ __launch_bounds__(256) void bn_stats_kernel(const float* __restrict__ h,
                                                       float* __restrict__ stats, int n) {
    int c = threadIdx.x & 127;
    int rt = (blockIdx.x * blockDim.x + threadIdx.x) >> 7;
    int rstride = (gridDim.x * blockDim.x) >> 7;
    float s = 0.0f, s2 = 0.0f;
    for (int r = rt; r < n; r += rstride) {
        float v = h[(size_t)r * HID + c];
        s += v; s2 += v * v;
    }
    atomicAdd(&stats[c], s);
    atomicAdd(&stats[HID + c], s2);
}

__global__ __launch_bounds__(256) void bn_apply_kernel(float* __restrict__ h,
                                                       const float* __restrict__ stats,
                                                       const float* __restrict__ gamma,
                                                       const float* __restrict__ beta,
                                                       int n) {
    int gid = blockIdx.x * blockDim.x + threadIdx.x;
    if (gid >= n * HID) return;
    int c = gid & 127;
    float inv_n = 1.0f / (float)n;
    float mean = stats[c] * inv_n;
    float var  = stats[HID + c] * inv_n - mean * mean;
    float sc = gamma[c] * rsqrtf(var + BN_EPS);
    float sh = beta[c] - mean * sc;
    h[gid] = fmaxf(h[gid] * sc + sh, 0.0f);
}

// ---------------------------------------------------------------------------
__global__ __launch_bounds__(256) void final_kernel(const float* __restrict__ h,
                                                    const float* __restrict__ lw,
                                                    const float* __restrict__ lb,
                                                    float* __restrict__ out, int n) {
    int wave = (int)((blockIdx.x * blockDim.x + threadIdx.x) >> 6);
    int lane = threadIdx.x & 63;
    if (wave >= n) return;
    const float* hr = h + (size_t)wave * HID;
    float logit = 0.0f;
    if (lane < OUT_DIM) {
        logit = lb[lane];
#pragma unroll 4
        for (int k = 0; k < HID; ++k)
            logit = fmaf(hr[k], lw[k * OUT_DIM + lane], logit);
    }
    float mx = (lane < OUT_DIM) ? logit : -INFINITY;
    for (int off = 32; off; off >>= 1) mx = fmaxf(mx, __shfl_xor(mx, off));
    float ex = (lane < OUT_DIM) ? expf(logit - mx) : 0.0f;
    float sum = ex;
    for (int off = 32; off; off >>= 1) sum += __shfl_xor(sum, off);
    if (lane < OUT_DIM) out[(size_t)wave * OUT_DIM + lane] = logit - mx - logf(sum);
}

// ---------------------------------------------------------------------------
extern "C" void kernel_launch(void* const* d_in, const int* in_sizes, int n_in,
                              void* d_out, int out_size, void* d_ws, size_t ws_size,
                              hipStream_t stream) {
    const float* x         = (const float*)d_in[0];
    const int*   ei        = (const int*)d_in[1];
    const float* log_alpha = (const float*)d_in[2];
    const float* log_beta  = (const float*)d_in[3];
    const float* mlp_w     = (const float*)d_in[4];
    const float* mlp_b     = (const float*)d_in[5];
    const float* conv_w    = (const float*)d_in[6];
    const float* conv_b    = (const float*)d_in[7];
    const float* bn_gamma  = (const float*)d_in[8];
    const float* bn_beta   = (const float*)d_in[9];
    const float* lin_w     = (const float*)d_in[10];
    const float* lin_b     = (const float*)d_in[11];
    float* out = (float*)d_out;

    const int n = N_NODES, E = N_EDGES;
    const int* src = ei;
    const int* dst = ei + E;

    // workspace layout (256B-aligned segments), total ~80.6 MB
    char* ws = (char*)d_ws;
    size_t off = 0;
    auto alloc = [&](size_t bytes) { char* p = ws + off; off += (bytes + 255) & ~(size_t)255; return p; };
    size_t hbytes = (size_t)n * HID * sizeof(float);        // 25.6 MB
    float*    hA     = (float*)alloc(hbytes);
    float*    hB     = (float*)alloc(hbytes);
    float*    hC     = (float*)alloc(hbytes);
    unsigned* rowptr = (unsigned*)alloc((size_t)(n + 1) * 4);
    unsigned* deg    = (unsigned*)alloc((size_t)n * 4);     // later reused as cursor
    float*    dinv   = (float*)alloc((size_t)n * 4);
    int*      ecol   = (int*)alloc((size_t)E * 4);          // 3.2 MB
    float*    stats  = (float*)alloc(512 * sizeof(float));
    unsigned* bsum   = (unsigned*)alloc(256 * 4);

    hipMemsetAsync(deg, 0, (size_t)n * 4, stream);
    hipMemsetAsync(stats, 0, 512 * sizeof(float), stream);

    const int B = 256;
    const int nscan = (n + SCAN_CHUNK - 1) / SCAN_CHUNK;   // 49
    count_deg_kernel<<<(E + B - 1) / B, B, 0, stream>>>(dst, deg, E);
    dinv_kernel<<<(n + B - 1) / B, B, 0, stream>>>(deg, dinv, n);
    scan_partial_kernel<<<nscan, B, 0, stream>>>(deg, bsum, n);
    scan_bsums_kernel<<<1, 64, 0, stream>>>(bsum, nscan);
    scan_chunk_kernel<<<nscan, B, 0, stream>>>(deg, bsum, rowptr, n);
    csr_fill_kernel<<<(E + B - 1) / B, B, 0, stream>>>(src, dst, deg, ecol, E);

    init_h_kernel<<<(n * HID + B - 1) / B, B, 0, stream>>>(x, log_alpha, log_beta, hA, n);

    int gemm_grid = (n + BM - 1) / BM;
    int ngrid = (n * HID + B - 1) / B;

    for (int i = 0; i < 3; ++i) {
        gemm128_v2_kernel<<<gemm_grid, B, 0, stream>>>(hA, mlp_w + (size_t)i * HID * HID,
                                                       mlp_b + (size_t)i * HID, hB, n, 1);
        gemm128_v2_kernel<<<gemm_grid, B, 0, stream>>>(hB, conv_w + (size_t)i * HID * HID,
                                                       nullptr, hC, n, 0);
        agg_csr_kernel<<<n, 128, 0, stream>>>(hC, dinv, conv_b + (size_t)i * HID,
                                              rowptr, ecol, hA);
        if (i < 2) {
            float* st = stats + (size_t)i * 256;
            bn_stats_kernel<<<512, B, 0, stream>>>(hA, st, n);
            bn_apply_kernel<<<ngrid, B, 0, stream>>>(hA, st, bn_gamma + (size_t)i * HID,
                                                     bn_beta + (size_t)i * HID, n);
        }
    }

    final_kernel<<<(n * 64 + B - 1) / B, B, 0, stream>>>(hA, lin_w, lin_b, out, n);
}

// Round 9
// 716.308 us; speedup vs baseline: 2.9724x; 1.0970x over previous
//
#include <hip/hip_runtime.h>
#include <hip/hip_bf16.h>
#include <math.h>

#define N_NODES 50000
#define N_EDGES 800000
#define HID 128
#define OUT_DIM 40
#define BN_EPS 1e-5f

// ---------------------------------------------------------------------------
// degree count by dst (real edges only; +1 self-loop applied in dinv)
__global__ __launch_bounds__(256) void count_deg_kernel(const int* __restrict__ dst,
                                                        unsigned* __restrict__ deg, int E) {
    int e = blockIdx.x * blockDim.x + threadIdx.x;
    if (e < E) atomicAdd(&deg[dst[e]], 1u);
}

__global__ __launch_bounds__(256) void dinv_kernel(const unsigned* __restrict__ deg,
                                                   float* __restrict__ dinv, int n) {
    int v = blockIdx.x * blockDim.x + threadIdx.x;
    if (v < n) dinv[v] = rsqrtf((float)(deg[v] + 1u));
}

// ---------------------------------------------------------------------------
// CSR build: 3-kernel exclusive scan of deg -> rowptr, then bucket fill.
// scan chunking: 1024 elements per block, 256 threads x 4 elems each.
#define SCAN_CHUNK 1024

__global__ __launch_bounds__(256) void scan_partial_kernel(const unsigned* __restrict__ deg,
                                                           unsigned* __restrict__ bsum, int n) {
    __shared__ unsigned sd[256];
    int base = blockIdx.x * SCAN_CHUNK;
    unsigned s = 0;
    for (int i = threadIdx.x; i < SCAN_CHUNK; i += 256) {
        int idx = base + i;
        if (idx < n) s += deg[idx];
    }
    sd[threadIdx.x] = s;
    __syncthreads();
    for (int off = 128; off; off >>= 1) {
        if (threadIdx.x < off) sd[threadIdx.x] += sd[threadIdx.x + off];
        __syncthreads();
    }
    if (threadIdx.x == 0) bsum[blockIdx.x] = sd[0];
}

// nb <= 64: single-thread exclusive scan (trivial work)
__global__ void scan_bsums_kernel(unsigned* __restrict__ bsum, int nb) {
    if (blockIdx.x == 0 && threadIdx.x == 0) {
        unsigned acc = 0;
        for (int i = 0; i < nb; ++i) { unsigned v = bsum[i]; bsum[i] = acc; acc += v; }
    }
}

// per-chunk exclusive scan -> rowptr[idx]; ALSO overwrites deg[idx] with the same
// value to serve as the csr_fill cursor. Sets rowptr[n] = E.
__global__ __launch_bounds__(256) void scan_chunk_kernel(unsigned* __restrict__ deg,
                                                         const unsigned* __restrict__ bsum,
                                                         unsigned* __restrict__ rowptr, int n) {
    __shared__ unsigned ts[256];
    int base = blockIdx.x * SCAN_CHUNK;
    int i0 = base + threadIdx.x * 4;
    unsigned v[4]; unsigned s = 0;
#pragma unroll
    for (int j = 0; j < 4; ++j) {
        int idx = i0 + j;
        v[j] = (idx < n) ? deg[idx] : 0u;
        s += v[j];
    }
    ts[threadIdx.x] = s;
    __syncthreads();
    // Hillis-Steele inclusive scan over 256 thread sums
    for (int off = 1; off < 256; off <<= 1) {
        unsigned add = (threadIdx.x >= (unsigned)off) ? ts[threadIdx.x - off] : 0u;
        __syncthreads();
        ts[threadIdx.x] += add;
        __syncthreads();
    }
    unsigned texcl = (threadIdx.x == 0) ? 0u : ts[threadIdx.x - 1];
    unsigned run = bsum[blockIdx.x] + texcl;
#pragma unroll
    for (int j = 0; j < 4; ++j) {
        int idx = i0 + j;
        if (idx < n) {
            rowptr[idx] = run;
            deg[idx] = run;          // cursor for csr_fill
            run += v[j];
            if (idx == n - 1) rowptr[n] = run;
        }
    }
}

__global__ __launch_bounds__(256) void csr_fill_kernel(const int* __restrict__ src,
                                                       const int* __restrict__ dst,
                                                       unsigned* __restrict__ cursor,
                                                       int* __restrict__ ecol, int E) {
    int e = blockIdx.x * blockDim.x + threadIdx.x;
    if (e >= E) return;
    unsigned pos = atomicAdd(&cursor[dst[e]], 1u);
    ecol[pos] = src[e];
}

// ---------------------------------------------------------------------------
// h0 = alpha * x[:, :128] + beta * x[:, 128:]
__global__ __launch_bounds__(256) void init_h_kernel(const float* __restrict__ x,
                                                     const float* __restrict__ log_alpha,
                                                     const float* __restrict__ log_beta,
                                                     float* __restrict__ h, int n) {
    int gid = blockIdx.x * blockDim.x + threadIdx.x;
    if (gid >= n * HID) return;
    int v = gid >> 7, c = gid & 127;
    float alpha = expf(log_alpha[0]);
    float beta  = expf(log_beta[0]);
    const float* xr = x + (size_t)v * (2 * HID);
    h[gid] = alpha * xr[c] + beta * xr[HID + c];
}

// ---------------------------------------------------------------------------
// GEMM v2: C[n x 128] = act(A @ W + bias). A-tile (64x128, 32 KB) in LDS;
// W (64 KB) read from L1/L2 via float4 (fully cache-resident, every block
// reads it). Thread = 4 cols (q) x 8 rows (rg): per k-step 8 broadcast
// ds_read_b32 + 1 coalesced global float4 + 32 FMA -> VALU-bound.
#define BM 64
__global__ __launch_bounds__(256) void gemm128_v2_kernel(const float* __restrict__ A,
                                                         const float* __restrict__ W,
                                                         const float* __restrict__ bias,
                                                         float* __restrict__ C,
                                                         int n, int do_relu) {
    __shared__ float As[BM][HID];  // 32 KB
    int row0 = blockIdx.x * BM;
    int nrow = min(BM, n - row0);
    {
        const float4* Ag = (const float4*)(A + (size_t)row0 * HID);
        float4* As4 = (float4*)&As[0][0];
        int n4 = nrow * (HID / 4);
        for (int i = threadIdx.x; i < n4; i += 256) As4[i] = Ag[i];
    }
    __syncthreads();

    int q  = threadIdx.x & 31;   // col quad: cols 4q..4q+3
    int rg = threadIdx.x >> 5;   // row group 0..7 -> rows 8rg..8rg+7
    int r0 = rg * 8;
    const float4* W4 = (const float4*)W;  // W4[k*32+q]

    float4 acc[8];
    float4 bv = make_float4(0.f, 0.f, 0.f, 0.f);
    if (bias) bv = ((const float4*)bias)[q];
#pragma unroll
    for (int i = 0; i < 8; ++i) acc[i] = bv;

#pragma unroll 4
    for (int k = 0; k < HID; ++k) {
        float4 w = W4[k * 32 + q];
#pragma unroll
        for (int i = 0; i < 8; ++i) {
            float a = As[r0 + i][k];
            acc[i].x = fmaf(a, w.x, acc[i].x);
            acc[i].y = fmaf(a, w.y, acc[i].y);
            acc[i].z = fmaf(a, w.z, acc[i].z);
            acc[i].w = fmaf(a, w.w, acc[i].w);
        }
    }

#pragma unroll
    for (int i = 0; i < 8; ++i) {
        int r = row0 + r0 + i;
        if (r < n) {
            float4 o = acc[i];
            if (do_relu) {
                o.x = fmaxf(o.x, 0.f); o.y = fmaxf(o.y, 0.f);
                o.z = fmaxf(o.z, 0.f); o.w = fmaxf(o.w, 0.f);
            }
            ((float4*)(C + (size_t)r * HID))[q] = o;
        }
    }
}

// ---------------------------------------------------------------------------
// CSR aggregation, one 128-thread block per node:
// out[v][c] = conv_b[c] + m[v][c]*dinv[v]^2 + sum_in-edges dinv[s]*dinv[v]*m[s][c]
__global__ __launch_bounds__(128) void agg_csr_kernel(const float* __restrict__ m,
                                                      const float* __restrict__ dinv,
                                                      const float* __restrict__ conv_b,
                                                      const unsigned* __restrict__ rowptr,
                                                      const int* __restrict__ ecol,
                                                      float* __restrict__ out) {
    int v = blockIdx.x;
    int c = threadIdx.x;
    float dv = dinv[v];
    float acc = conv_b[c] + m[(size_t)v * HID + c] * dv * dv;
    unsigned start = rowptr[v];
    unsigned end   = rowptr[v + 1];
    unsigned i = start;
    // 2-wide to break the ecol->m dependent-load chain
    for (; i + 1 < end; i += 2) {
        int s0 = ecol[i], s1 = ecol[i + 1];
        float w0 = dinv[s0] * dv, w1 = dinv[s1] * dv;
        acc = fmaf(w0, m[(size_t)s0 * HID + c], acc);
        acc = fmaf(w1, m[(size_t)s1 * HID + c], acc);
    }
    if (i < end) {
        int s0 = ecol[i];
        acc = fmaf(dinv[s0] * dv, m[(size_t)s0 * HID + c], acc);
    }
    out[(size_t)v * HID + c] = acc;
}

// ---------------------------------------------------------------------------
__global__ __launch_bounds__(256) void bn_stats_kernel(const float* __restrict__ h,
                                                       float* __restrict__ stats, int n) {
    int c = threadIdx.x & 127;
    int rt = (blockIdx.x * blockDim.x + threadIdx.x) >> 7;
    int rstride = (gridDim.x * blockDim.x) >> 7;
    float s = 0.0f, s2 = 0.0f;
    for (int r = rt; r < n; r += rstride) {
        float v = h[(size_t)r * HID + c];
        s += v; s2 += v * v;
    }
    atomicAdd(&stats[c], s);
    atomicAdd(&stats[HID + c], s2);
}

__global__ __launch_bounds__(256) void bn_apply_kernel(float* __restrict__ h,
                                                       const float* __restrict__ stats,
                                                       const float* __restrict__ gamma,
                                                       const float* __restrict__ beta,
                                                       int n) {
    int gid = blockIdx.x * blockDim.x + threadIdx.x;
    if (gid >= n * HID) return;
    int c = gid & 127;
    float inv_n = 1.0f / (float)n;
    float mean = stats[c] * inv_n;
    float var  = stats[HID + c] * inv_n - mean * mean;
    float sc = gamma[c] * rsqrtf(var + BN_EPS);
    float sh = beta[c] - mean * sc;
    h[gid] = fmaxf(h[gid] * sc + sh, 0.0f);
}

// ---------------------------------------------------------------------------
// final v2: logits = h @ lw + lb, then log_softmax.
// Block = 256 threads / 32 rows; lw (128x40 = 20 KB) in LDS -> 8 blocks/CU
// (exactly 160 KB LDS, full 2048-thread occupancy). Wave = 8 rows; 8 lanes
// per row; each lane owns 5 cols (5 independent accumulators -> ILP 5, all
// 64 lanes active). h read as float4, broadcast within the 8-lane row group.
// LDS reads lws[k][sub*5+i]: stride-5 across subs, gcd(5,32)=1 -> conflict-free.
#define FB_ROWS 32
__global__ __launch_bounds__(256) void final_v2_kernel(const float* __restrict__ h,
                                                       const float* __restrict__ lw,
                                                       const float* __restrict__ lb,
                                                       float* __restrict__ out, int n) {
    __shared__ float lws[HID * OUT_DIM];  // 20 KB, [k][c] row-major
    for (int i = threadIdx.x; i < HID * OUT_DIM; i += 256) lws[i] = lw[i];
    __syncthreads();

    int wave = threadIdx.x >> 6;           // 0..3
    int lane = threadIdx.x & 63;
    int rw   = lane >> 3;                  // row within wave: 0..7
    int sub  = lane & 7;                   // col-group owner: 0..7
    int r = blockIdx.x * FB_ROWS + wave * 8 + rw;
    if (r >= n) return;

    int c0 = sub * 5;
    float acc[5];
#pragma unroll
    for (int i = 0; i < 5; ++i) acc[i] = lb[c0 + i];

    const float4* hr4 = (const float4*)(h + (size_t)r * HID);
#pragma unroll 4
    for (int k4 = 0; k4 < HID / 4; ++k4) {
        float4 hv = hr4[k4];               // broadcast among the 8 lanes of this row
        int kb = k4 * 4;
#pragma unroll
        for (int j = 0; j < 4; ++j) {
            float a = (j == 0) ? hv.x : (j == 1) ? hv.y : (j == 2) ? hv.z : hv.w;
            const float* wr = &lws[(kb + j) * OUT_DIM + c0];
#pragma unroll
            for (int i = 0; i < 5; ++i) acc[i] = fmaf(a, wr[i], acc[i]);
        }
    }

    // row max over 40 values: per-lane max of 5, then xor-reduce within 8 lanes
    float mx = acc[0];
#pragma unroll
    for (int i = 1; i < 5; ++i) mx = fmaxf(mx, acc[i]);
    for (int off = 4; off; off >>= 1) mx = fmaxf(mx, __shfl_xor(mx, off));

    float s = 0.0f;
#pragma unroll
    for (int i = 0; i < 5; ++i) s += expf(acc[i] - mx);
    for (int off = 4; off; off >>= 1) s += __shfl_xor(s, off);
    float lse = mx + logf(s);

    float* orow = out + (size_t)r * OUT_DIM + c0;
#pragma unroll
    for (int i = 0; i < 5; ++i) orow[i] = acc[i] - lse;
}

// ---------------------------------------------------------------------------
extern "C" void kernel_launch(void* const* d_in, const int* in_sizes, int n_in,
                              void* d_out, int out_size, void* d_ws, size_t ws_size,
                              hipStream_t stream) {
    const float* x         = (const float*)d_in[0];
    const int*   ei        = (const int*)d_in[1];
    const float* log_alpha = (const float*)d_in[2];
    const float* log_beta  = (const float*)d_in[3];
    const float* mlp_w     = (const float*)d_in[4];
    const float* mlp_b     = (const float*)d_in[5];
    const float* conv_w    = (const float*)d_in[6];
    const float* conv_b    = (const float*)d_in[7];
    const float* bn_gamma  = (const float*)d_in[8];
    const float* bn_beta   = (const float*)d_in[9];
    const float* lin_w     = (const float*)d_in[10];
    const float* lin_b     = (const float*)d_in[11];
    float* out = (float*)d_out;

    const int n = N_NODES, E = N_EDGES;
    const int* src = ei;
    const int* dst = ei + E;

    // workspace layout (256B-aligned segments), total ~80.6 MB
    char* ws = (char*)d_ws;
    size_t off = 0;
    auto alloc = [&](size_t bytes) { char* p = ws + off; off += (bytes + 255) & ~(size_t)255; return p; };
    size_t hbytes = (size_t)n * HID * sizeof(float);        // 25.6 MB
    float*    hA     = (float*)alloc(hbytes);
    float*    hB     = (float*)alloc(hbytes);
    float*    hC     = (float*)alloc(hbytes);
    unsigned* rowptr = (unsigned*)alloc((size_t)(n + 1) * 4);
    unsigned* deg    = (unsigned*)alloc((size_t)n * 4);     // later reused as cursor
    float*    dinv   = (float*)alloc((size_t)n * 4);
    int*      ecol   = (int*)alloc((size_t)E * 4);          // 3.2 MB
    float*    stats  = (float*)alloc(512 * sizeof(float));
    unsigned* bsum   = (unsigned*)alloc(256 * 4);

    hipMemsetAsync(deg, 0, (size_t)n * 4, stream);
    hipMemsetAsync(stats, 0, 512 * sizeof(float), stream);

    const int B = 256;
    const int nscan = (n + SCAN_CHUNK - 1) / SCAN_CHUNK;   // 49
    count_deg_kernel<<<(E + B - 1) / B, B, 0, stream>>>(dst, deg, E);
    dinv_kernel<<<(n + B - 1) / B, B, 0, stream>>>(deg, dinv, n);
    scan_partial_kernel<<<nscan, B, 0, stream>>>(deg, bsum, n);
    scan_bsums_kernel<<<1, 64, 0, stream>>>(bsum, nscan);
    scan_chunk_kernel<<<nscan, B, 0, stream>>>(deg, bsum, rowptr, n);
    csr_fill_kernel<<<(E + B - 1) / B, B, 0, stream>>>(src, dst, deg, ecol, E);

    init_h_kernel<<<(n * HID + B - 1) / B, B, 0, stream>>>(x, log_alpha, log_beta, hA, n);

    int gemm_grid = (n + BM - 1) / BM;
    int ngrid = (n * HID + B - 1) / B;

    for (int i = 0; i < 3; ++i) {
        gemm128_v2_kernel<<<gemm_grid, B, 0, stream>>>(hA, mlp_w + (size_t)i * HID * HID,
                                                       mlp_b + (size_t)i * HID, hB, n, 1);
        gemm128_v2_kernel<<<gemm_grid, B, 0, stream>>>(hB, conv_w + (size_t)i * HID * HID,
                                                       nullptr, hC, n, 0);
        agg_csr_kernel<<<n, 128, 0, stream>>>(hC, dinv, conv_b + (size_t)i * HID,
                                              rowptr, ecol, hA);
        if (i < 2) {
            float* st = stats + (size_t)i * 256;
            bn_stats_kernel<<<512, B, 0, stream>>>(hA, st, n);
            bn_apply_kernel<<<ngrid, B, 0, stream>>>(hA, st, bn_gamma + (size_t)i * HID,
                                                     bn_beta + (size_t)i * HID, n);
        }
    }

    final_v2_kernel<<<(n + FB_ROWS - 1) / FB_ROWS, B, 0, stream>>>(hA, lin_w, lin_b, out, n);
}